// Round 13
// baseline (225.905 us; speedup 1.0000x reference)
//
#include <hip/hip_runtime.h>
#include <hip/hip_bf16.h>

#define NB 2
#define NL 2048
#define NH 12
#define ND 64
#define NEWTON 6
#define WV 8            // waves per block (attn)
#define TPW 16          // key-tiles per wave = 128/WV
#define QPB 6           // q-tiles per persistent block (512 blocks x 6 = 3072)

typedef __bf16 bf16x8 __attribute__((ext_vector_type(8)));
typedef float f32x4 __attribute__((ext_vector_type(4)));
typedef float f32x2 __attribute__((ext_vector_type(2)));

// DPP row_ror reductions within each 16-lane row.
#define ROR_ADD(v, n)                                                         \
  (v) += __int_as_float(__builtin_amdgcn_update_dpp(                          \
      0, __float_as_int(v), 0x120 + (n), 0xF, 0xF, true))
#define ROR_MAX(v, n)                                                         \
  (v) = fmaxf((v), __int_as_float(__builtin_amdgcn_update_dpp(                \
                  0, __float_as_int(v), 0x120 + (n), 0xF, 0xF, true)))

// ---- prep: block = (b, kt16, head-group of 4) x {K,V}. 1536 blocks, 256 thr,
// 16.6 KB LDS. Single-bf16 pack (no hi/lo): error analysis shows the final
// y = negc - x ~ 38 makes weight sensitivity to score error ~3.7e-5 — bf16
// operand rounding stays below the output quantization floor (absmax pinned
// at 2^-10 across rounds, threshold 3.9e-3).
__global__ __launch_bounds__(256) void prep(
    const float* __restrict__ kg, const float* __restrict__ vg,
    __bf16* __restrict__ kp, __bf16* __restrict__ vp) {
  __shared__ __align__(16) float kv[16][260];  // [key][4 heads x 64 d]
  const int blk = blockIdx.x;
  const int isV = blk >= NB * 128 * 3;
  const int bk = isV ? blk - NB * 128 * 3 : blk;
  const int hg = bk % 3;
  const int kt = (bk / 3) & 127;
  const int b = bk / 384;
  const int t = threadIdx.x;
  const int w = t >> 6;           // wave 0..3 == local head
  const int lane = t & 63;
  const int quad = lane >> 4;
  const int l16 = lane & 15;

  const float* __restrict__ src = isV ? vg : kg;
#pragma unroll
  for (int i = 0; i < 4; ++i) {
    const int f = i * 1024 + t * 4;
    const int key = f >> 8;
    const int rem = f & 255;
    const size_t s =
        (size_t)(b * NL + kt * 16 + key) * (NH * ND) + hg * 256 + rem;
    *(f32x4*)(&kv[key][rem]) = *(const f32x4*)(src + s);
  }
  __syncthreads();

  const int h = hg * 4 + w;

  if (!isV) {
    // ---- K pack (single bf16) ----
    const float* p = &kv[l16][w * 64 + quad * 8];
    f32x4 a0 = *(const f32x4*)(p);
    f32x4 a1 = *(const f32x4*)(p + 4);
    f32x4 a2 = *(const f32x4*)(p + 32);
    f32x4 a3 = *(const f32x4*)(p + 36);
    bf16x8 h0, h1;
#pragma unroll
    for (int j = 0; j < 4; ++j) {
      h0[j] = (__bf16)a0[j];
      h0[4 + j] = (__bf16)a1[j];
      h1[j] = (__bf16)a2[j];
      h1[4 + j] = (__bf16)a3[j];
    }
    const size_t basek =
        ((size_t)((b * NH + h) * 128 + kt) * 2) * 512 + lane * 8;
    *(bf16x8*)(kp + basek) = h0;
    *(bf16x8*)(kp + basek + 512) = h1;
  } else {
    // ---- V pack (single bf16) ----
    const int halfsel = (kt >> 3) & 1;
    const int pi = (kt >> 4) * 8 + (kt & 7);
    const int q2 = quad & 1;
    const int nhalf = quad >> 1;
    const int qdst = 2 * halfsel + q2;
#pragma unroll
    for (int nn = 0; nn < 2; ++nn) {
      const int n = nhalf * 2 + nn;
      bf16x8 hv;
#pragma unroll
      for (int j = 0; j < 8; ++j)
        hv[j] = (__bf16)kv[q2 * 8 + j][w * 64 + n * 16 + l16];
      const size_t off =
          ((((size_t)(b * NH + h) * 64 + pi) * 4 + n) * 64 + qdst * 16 + l16) * 8;
      *(bf16x8*)(vp + off) = hv;
    }
  }
}

// ---------------- main fused attention-poly kernel ----------------
// Persistent-block form: 512 blocks (exactly 2/CU), each loops over 6
// consecutive slots of its XCD — removes 5 of 6 occupancy-generation
// ramp/drain cycles and keeps K/V L2-hot across a block's q-tiles.
// Single-bf16 operands (r11); phases 4+5 merged via per-wave dbuf slabs (r12).
// History: AGPR alloc for y (64 f32) + ~52 arch regs pins occupancy at
// 2 blocks/CU (4 waves/SIMD); (512,6) spills y (r5) — keep (512,4).
__launch_bounds__(512, 4)
__global__ void attn_poly(const float* __restrict__ qg,
                          const __bf16* __restrict__ kp,
                          const __bf16* __restrict__ vp,
                          float* __restrict__ outg) {
  // Per-wave union: phase-5 weight slab overlays phase-6 partial slab.
  // Each wave only touches its own pw[w] until the phase-6 barrier; the
  // end-of-qtile barrier protects the ex->ws overlay across loop iterations.
  struct PW {
    union {
      float ex[16][68];          // phase 6 partials (4352 B)
      __bf16 ws[2][16][40];      // phase 5 dbuf weight slabs (2560 B)
    };
  };
  __shared__ __align__(16) PW pw[WV];
  __shared__ float redmax[WV][17];
  __shared__ float redn[NEWTON][16][2];   // per-iteration atomic sum buffers

  const int tid = threadIdx.x;
  const int w = tid >> 6;
  const int lane = tid & 63;
  const int quad = lane >> 4;
  const int l16 = lane & 15;

  // XCD-aware mapping: blocks dispatch round-robin over 8 XCDs (blk&7).
  // Each XCD owns bh in [xcd*3, xcd*3+3) (384 slots = 3 bh x 128 qt);
  // block idx (0..63) within the XCD handles slots idx*6 .. idx*6+5.
  const int blk = blockIdx.x;
  const int xcd = blk & 7;
  const int idx = blk >> 3;            // 0..63 within this XCD

#pragma unroll 1
  for (int qi = 0; qi < QPB; ++qi) {
    const int slot = idx * QPB + qi;   // 0..383
    const int bh = xcd * 3 + (slot >> 7);
    const int qt = slot & 127;
    const int h = bh % NH;
    const int b = bh / NH;
    const int qbase = qt * 16;

    // ---- Q fragments: fp32 * 0.125 -> bf16 ----
    bf16x8 q0, q1;
    {
      const float* qp = qg + ((b * NL + qbase + l16) * NH + h) * ND + quad * 8;
      f32x4 a0 = *(const f32x4*)(qp);
      f32x4 a1 = *(const f32x4*)(qp + 4);
      f32x4 a2 = *(const f32x4*)(qp + 32);
      f32x4 a3 = *(const f32x4*)(qp + 36);
#pragma unroll
      for (int j = 0; j < 4; ++j) {
        q0[j] = (__bf16)(a0[j] * 0.125f);
        q0[4 + j] = (__bf16)(a1[j] * 0.125f);
        q1[j] = (__bf16)(a2[j] * 0.125f);
        q1[4 + j] = (__bf16)(a3[j] * 0.125f);
      }
    }

    // ---- phase 1: S = (Q/8) Kt ; y[t][j] = rows (quad*4+2j,+2j+1), col l16 ----
    f32x2 y[TPW][2];
    {
      const __bf16* kb = kp + (size_t)bh * 131072;
#pragma unroll
      for (int t = 0; t < TPW; ++t) {
        const int ktile = w + WV * t;
        const size_t o = (size_t)ktile * 1024 + lane * 8;
        bf16x8 k0 = *(const bf16x8*)(kb + o);
        bf16x8 k1 = *(const bf16x8*)(kb + o + 512);
        f32x4 acc = {0.f, 0.f, 0.f, 0.f};
        acc = __builtin_amdgcn_mfma_f32_16x16x32_bf16(q0, k0, acc, 0, 0, 0);
        acc = __builtin_amdgcn_mfma_f32_16x16x32_bf16(q1, k1, acc, 0, 0, 0);
        y[t][0] = __builtin_shufflevector(acc, acc, 0, 1);
        y[t][1] = __builtin_shufflevector(acc, acc, 2, 3);
      }
    }

    // ---- phase 2: row max -> negc[j] = -c0 pairs (= max+1); y := negc - s ----
    {
      f32x2 mx2[2] = {y[0][0], y[0][1]};
#pragma unroll
      for (int t = 1; t < TPW; ++t) {
#pragma unroll
        for (int j = 0; j < 2; ++j) {
          mx2[j].x = fmaxf(mx2[j].x, y[t][j].x);
          mx2[j].y = fmaxf(mx2[j].y, y[t][j].y);
        }
      }
#pragma unroll
      for (int j = 0; j < 2; ++j) {
        ROR_MAX(mx2[j].x, 8); ROR_MAX(mx2[j].x, 4); ROR_MAX(mx2[j].x, 2); ROR_MAX(mx2[j].x, 1);
        ROR_MAX(mx2[j].y, 8); ROR_MAX(mx2[j].y, 4); ROR_MAX(mx2[j].y, 2); ROR_MAX(mx2[j].y, 1);
      }
      if (l16 < 4) {
        float v = (l16 == 0) ? mx2[0].x : (l16 == 1) ? mx2[0].y
                : (l16 == 2) ? mx2[1].x : mx2[1].y;
        redmax[w][quad * 4 + l16] = v;
      }
      // zero the Newton atomic buffers under the same barrier
      if (tid < NEWTON * 16 * 2) ((float*)redn)[tid] = 0.f;
      __syncthreads();
      f32x2 negc[2];
#pragma unroll
      for (int r = 0; r < 4; ++r) {
        float m = redmax[l16 & 7][quad * 4 + r];
        ROR_MAX(m, 4); ROR_MAX(m, 2); ROR_MAX(m, 1);
        ((float*)negc)[r] = m + 1.0f;            // -c0 = max + 1
      }
      // convert scores -> y0 = negc0 - s  (in place)
#pragma unroll
      for (int t = 0; t < TPW; ++t) {
        y[t][0] = negc[0] - y[t][0];
        y[t][1] = negc[1] - y[t][1];
      }
    }

    // ---- phase 3: Newton x6 (packed-f32 inner loop; cross-wave via ds_add) ----
    for (int it = 0; it < NEWTON; ++it) {
      f32x2 ps2[2] = {{0.f, 0.f}, {0.f, 0.f}};
      f32x2 psd2[2] = {{0.f, 0.f}, {0.f, 0.f}};
#pragma unroll
      for (int t = 0; t < TPW; ++t) {
#pragma unroll
        for (int j = 0; j < 2; ++j) {
          f32x2 v = y[t][j];                     // y >= 1 along Newton path
          float z = __builtin_amdgcn_rcpf(v.x * v.y);
          f32x2 r1 = z * __builtin_shufflevector(v, v, 1, 0);  // (1/y.x, 1/y.y)
          f32x2 r2;
          asm("v_pk_mul_f32 %0, %1, %1" : "=v"(r2) : "v"(r1));
          asm("v_pk_add_f32 %0, %0, %1" : "+v"(ps2[j]) : "v"(r2));
          asm("v_pk_fma_f32 %0, %1, %2, %0" : "+v"(psd2[j]) : "v"(r2), "v"(r1));
        }
      }
#pragma unroll
      for (int j = 0; j < 2; ++j) {
        ROR_ADD(ps2[j].x, 8);  ROR_ADD(ps2[j].x, 4);  ROR_ADD(ps2[j].x, 2);  ROR_ADD(ps2[j].x, 1);
        ROR_ADD(ps2[j].y, 8);  ROR_ADD(ps2[j].y, 4);  ROR_ADD(ps2[j].y, 2);  ROR_ADD(ps2[j].y, 1);
        ROR_ADD(psd2[j].x, 8); ROR_ADD(psd2[j].x, 4); ROR_ADD(psd2[j].x, 2); ROR_ADD(psd2[j].x, 1);
        ROR_ADD(psd2[j].y, 8); ROR_ADD(psd2[j].y, 4); ROR_ADD(psd2[j].y, 2); ROR_ADD(psd2[j].y, 1);
      }
      if (l16 < 4) {
        float a = (l16 == 0) ? ps2[0].x : (l16 == 1) ? ps2[0].y
                : (l16 == 2) ? ps2[1].x : ps2[1].y;
        float d = (l16 == 0) ? psd2[0].x : (l16 == 1) ? psd2[0].y
                : (l16 == 2) ? psd2[1].x : psd2[1].y;
        atomicAdd(&redn[it][quad * 4 + l16][0], a);
        atomicAdd(&redn[it][quad * 4 + l16][1], d);
      }
      __syncthreads();
      f32x2 dd[2];
#pragma unroll
      for (int r = 0; r < 4; ++r) {
        const f32x2 v = *(const f32x2*)(&redn[it][quad * 4 + r][0]);
        ((float*)dd)[r] =
            (v.x - 1.0f) * __builtin_amdgcn_rcpf(2.0f * v.y + 1e-8f);
      }
#pragma unroll
      for (int t = 0; t < TPW; ++t) {
        y[t][0] += dd[0];
        y[t][1] += dd[1];
      }
    }

    // ---- phase 5: O = W * V; per-wave double-buffered bf16 weight slab ----
    f32x4 oacc[4];
#pragma unroll
    for (int n = 0; n < 4; ++n) oacc[n] = (f32x4){0.f, 0.f, 0.f, 0.f};
    const __bf16* vpb = vp + (size_t)bh * 131072;

    // prologue: weights for tiles 0,1 -> buf 0
#pragma unroll
    for (int ts = 0; ts < 2; ++ts) {
      f32x2 a = y[ts][0];
      f32x2 bb = y[ts][1];
      float za = __builtin_amdgcn_rcpf(a.x * a.y);
      float zb = __builtin_amdgcn_rcpf(bb.x * bb.y);
      f32x2 ra = za * __builtin_shufflevector(a, a, 1, 0);
      f32x2 rb = zb * __builtin_shufflevector(bb, bb, 1, 0);
      f32x2 wa = ra * ra;
      f32x2 wb = rb * rb;
      pw[w].ws[0][quad * 4 + 0][ts * 16 + l16] = (__bf16)wa.x;
      pw[w].ws[0][quad * 4 + 1][ts * 16 + l16] = (__bf16)wa.y;
      pw[w].ws[0][quad * 4 + 2][ts * 16 + l16] = (__bf16)wb.x;
      pw[w].ws[0][quad * 4 + 3][ts * 16 + l16] = (__bf16)wb.y;
    }

#pragma unroll
    for (int p = 0; p < 8; ++p) {
      const size_t vo = ((size_t)(p * 8 + w) * 4) * 512 + lane * 8;
      // V loads (independent of slab) issue first
      bf16x8 v0 = *(const bf16x8*)(vpb + vo);
      bf16x8 v1 = *(const bf16x8*)(vpb + vo + 512);
      bf16x8 v2 = *(const bf16x8*)(vpb + vo + 1024);
      bf16x8 v3 = *(const bf16x8*)(vpb + vo + 1536);

      asm volatile("s_waitcnt lgkmcnt(0)" ::: "memory");  // slab writes visible
      // A-fragment: row l16, keys of tiles 2p (quads 0-1) / 2p+1 (quads 2-3):
      // col = (quad>>1)*16 + (quad&1)*8 + j == quad*8 + j.
      bf16x8 aw = *(const bf16x8*)(&pw[w].ws[p & 1][l16][quad * 8]);

      // write NEXT iteration's weights into the other buffer (no wait needed)
      if (p < 7) {
#pragma unroll
        for (int ts = 0; ts < 2; ++ts) {
          const int t = 2 * (p + 1) + ts;
          f32x2 a = y[t][0];
          f32x2 bb = y[t][1];
          float za = __builtin_amdgcn_rcpf(a.x * a.y);
          float zb = __builtin_amdgcn_rcpf(bb.x * bb.y);
          f32x2 ra = za * __builtin_shufflevector(a, a, 1, 0);
          f32x2 rb = zb * __builtin_shufflevector(bb, bb, 1, 0);
          f32x2 wa = ra * ra;
          f32x2 wb = rb * rb;
          pw[w].ws[(p + 1) & 1][quad * 4 + 0][ts * 16 + l16] = (__bf16)wa.x;
          pw[w].ws[(p + 1) & 1][quad * 4 + 1][ts * 16 + l16] = (__bf16)wa.y;
          pw[w].ws[(p + 1) & 1][quad * 4 + 2][ts * 16 + l16] = (__bf16)wb.x;
          pw[w].ws[(p + 1) & 1][quad * 4 + 3][ts * 16 + l16] = (__bf16)wb.y;
        }
      }

      oacc[0] = __builtin_amdgcn_mfma_f32_16x16x32_bf16(aw, v0, oacc[0], 0, 0, 0);
      oacc[1] = __builtin_amdgcn_mfma_f32_16x16x32_bf16(aw, v1, oacc[1], 0, 0, 0);
      oacc[2] = __builtin_amdgcn_mfma_f32_16x16x32_bf16(aw, v2, oacc[2], 0, 0, 0);
      oacc[3] = __builtin_amdgcn_mfma_f32_16x16x32_bf16(aw, v3, oacc[3], 0, 0, 0);
    }

    // ---- phase 6: reduce partials across waves, write global ----
#pragma unroll
    for (int n = 0; n < 4; ++n)
#pragma unroll
      for (int r = 0; r < 4; ++r)
        pw[w].ex[quad * 4 + r][n * 16 + l16] = oacc[n][r];
    __syncthreads();
    {
      const int row = 2 * w + (lane >> 5);
      const int d = lane & 31;
      float v0 = 0.f, v1 = 0.f;
#pragma unroll
      for (int i = 0; i < WV; ++i) {
        v0 += pw[i].ex[row][d];
        v1 += pw[i].ex[row][d + 32];
      }
      const int off = ((b * NL + qbase + row) * NH + h) * ND + d;
      outg[off] = v0;
      outg[off + 32] = v1;
    }
    // All waves' ex reads complete before next qtile overwrites pw (ws).
    __syncthreads();
  }
}

extern "C" void kernel_launch(void* const* d_in, const int* in_sizes, int n_in,
                              void* d_out, int out_size, void* d_ws, size_t ws_size,
                              hipStream_t stream) {
  const float* q = (const float*)d_in[0];
  const float* k = (const float*)d_in[1];
  const float* v = (const float*)d_in[2];

  const size_t plane = (size_t)NB * NH * ND * NL;  // 3.15M elems, 6.29MB/plane
  __bf16* kp = (__bf16*)d_ws;
  __bf16* vp = kp + plane;

  prep<<<NB * 128 * 3 * 2, 256, 0, stream>>>(k, v, kp, vp);

  attn_poly<<<512, 512, 0, stream>>>(q, kp, vp, (float*)d_out);
}

// Round 14
// 212.562 us; speedup vs baseline: 1.0628x; 1.0628x over previous
//
#include <hip/hip_runtime.h>
#include <hip/hip_bf16.h>

#define NB 2
#define NL 2048
#define NH 12
#define ND 64
#define NEWTON 6
#define WV 8            // waves per block (attn)
#define TPW 16          // key-tiles per wave = 128/WV

typedef __bf16 bf16x8 __attribute__((ext_vector_type(8)));
typedef float f32x4 __attribute__((ext_vector_type(4)));
typedef float f32x2 __attribute__((ext_vector_type(2)));

// DPP row_ror reductions within each 16-lane row.
#define ROR_ADD(v, n)                                                         \
  (v) += __int_as_float(__builtin_amdgcn_update_dpp(                          \
      0, __float_as_int(v), 0x120 + (n), 0xF, 0xF, true))
#define ROR_MAX(v, n)                                                         \
  (v) = fmaxf((v), __int_as_float(__builtin_amdgcn_update_dpp(                \
                  0, __float_as_int(v), 0x120 + (n), 0xF, 0xF, true)))

// ---- prep: block = (b, kt16, head-group of 4) x {K,V}. 1536 blocks, 256 thr,
// 16.6 KB LDS. Single-bf16 pack (no hi/lo): error analysis shows the final
// y = negc - x ~ 38 makes weight sensitivity to score error ~3.7e-5 — bf16
// operand rounding stays below the output quantization floor (absmax pinned
// at 2^-10 across rounds, threshold 3.9e-3).
__global__ __launch_bounds__(256) void prep(
    const float* __restrict__ kg, const float* __restrict__ vg,
    __bf16* __restrict__ kp, __bf16* __restrict__ vp) {
  __shared__ __align__(16) float kv[16][260];  // [key][4 heads x 64 d]
  const int blk = blockIdx.x;
  const int isV = blk >= NB * 128 * 3;
  const int bk = isV ? blk - NB * 128 * 3 : blk;
  const int hg = bk % 3;
  const int kt = (bk / 3) & 127;
  const int b = bk / 384;
  const int t = threadIdx.x;
  const int w = t >> 6;           // wave 0..3 == local head
  const int lane = t & 63;
  const int quad = lane >> 4;
  const int l16 = lane & 15;

  const float* __restrict__ src = isV ? vg : kg;
#pragma unroll
  for (int i = 0; i < 4; ++i) {
    const int f = i * 1024 + t * 4;
    const int key = f >> 8;
    const int rem = f & 255;
    const size_t s =
        (size_t)(b * NL + kt * 16 + key) * (NH * ND) + hg * 256 + rem;
    *(f32x4*)(&kv[key][rem]) = *(const f32x4*)(src + s);
  }
  __syncthreads();

  const int h = hg * 4 + w;

  if (!isV) {
    // ---- K pack (single bf16) ----
    const float* p = &kv[l16][w * 64 + quad * 8];
    f32x4 a0 = *(const f32x4*)(p);
    f32x4 a1 = *(const f32x4*)(p + 4);
    f32x4 a2 = *(const f32x4*)(p + 32);
    f32x4 a3 = *(const f32x4*)(p + 36);
    bf16x8 h0, h1;
#pragma unroll
    for (int j = 0; j < 4; ++j) {
      h0[j] = (__bf16)a0[j];
      h0[4 + j] = (__bf16)a1[j];
      h1[j] = (__bf16)a2[j];
      h1[4 + j] = (__bf16)a3[j];
    }
    const size_t basek =
        ((size_t)((b * NH + h) * 128 + kt) * 2) * 512 + lane * 8;
    *(bf16x8*)(kp + basek) = h0;
    *(bf16x8*)(kp + basek + 512) = h1;
  } else {
    // ---- V pack (single bf16) ----
    const int halfsel = (kt >> 3) & 1;
    const int pi = (kt >> 4) * 8 + (kt & 7);
    const int q2 = quad & 1;
    const int nhalf = quad >> 1;
    const int qdst = 2 * halfsel + q2;
#pragma unroll
    for (int nn = 0; nn < 2; ++nn) {
      const int n = nhalf * 2 + nn;
      bf16x8 hv;
#pragma unroll
      for (int j = 0; j < 8; ++j)
        hv[j] = (__bf16)kv[q2 * 8 + j][w * 64 + n * 16 + l16];
      const size_t off =
          ((((size_t)(b * NH + h) * 64 + pi) * 4 + n) * 64 + qdst * 16 + l16) * 8;
      *(bf16x8*)(vp + off) = hv;
    }
  }
}

// ---------------- main fused attention-poly kernel ----------------
// Single-bf16 operands (r11). Phases 4+5 merged via per-wave double-buffered
// weight slabs (r12): each wave's PV tiles (pi=8p+w <-> score tiles 2p,2p+1
// of wave w) consume only weights that wave computes, so the weight handoff
// needs NO block barriers — just an lgkmcnt wait.
// History: AGPR-shuttle theory refuted (r7 budget, r8-r10 pins all null) —
// VALU reads the AGPR-resident y directly at no extra cost. (512,6) spills
// y (r5) — keep (512,4). Occupancy structurally pinned at 2 blocks/CU
// (4 waves/SIMD) by y[16][2] (64 f32 in AGPR) + ~52 arch regs.
// r13: persistent blocks (512 x 6 q-tiles) REGRESSED 155->171us — the HW
// dispatcher already back-fills block slots (generations overlap); persistence
// loses that load balancing. Keep the flat 3072-block grid.
__launch_bounds__(512, 4)
__global__ void attn_poly(const float* __restrict__ qg,
                          const __bf16* __restrict__ kp,
                          const __bf16* __restrict__ vp,
                          float* __restrict__ outg) {
  // Per-wave union: phase-5 weight slab overlays phase-6 partial slab.
  // Each wave only touches its own pw[w] until the phase-6 barrier, and the
  // last ws read (p=7) precedes the first ex write in program order (DS ops
  // are in-order per wave), so the overlay is race-free.
  struct PW {
    union {
      float ex[16][68];          // phase 6 partials (4352 B)
      __bf16 ws[2][16][40];      // phase 5 dbuf weight slabs (2560 B)
    };
  };
  __shared__ __align__(16) PW pw[WV];
  __shared__ float redmax[WV][17];
  __shared__ float redn[NEWTON][16][2];   // per-iteration atomic sum buffers

  const int tid = threadIdx.x;
  const int w = tid >> 6;
  const int lane = tid & 63;
  const int quad = lane >> 4;
  const int l16 = lane & 15;

  // XCD-aware swizzle: blocks dispatch round-robin over 8 XCDs (blk&7).
  // Each XCD gets 3 complete bh groups so its concurrent block window shares
  // one bh -> K/V L2-resident (FETCH 104MB -> 18.5MB, round 4).
  const int blk = blockIdx.x;
  const int xcd = blk & 7;
  const int slot = blk >> 3;           // 0..383 within this XCD
  const int bh = xcd * 3 + (slot >> 7);
  const int qt = slot & 127;
  const int h = bh % NH;
  const int b = bh / NH;
  const int qbase = qt * 16;

  // ---- Q fragments: fp32 * 0.125 -> bf16 ----
  bf16x8 q0, q1;
  {
    const float* qp = qg + ((b * NL + qbase + l16) * NH + h) * ND + quad * 8;
    f32x4 a0 = *(const f32x4*)(qp);
    f32x4 a1 = *(const f32x4*)(qp + 4);
    f32x4 a2 = *(const f32x4*)(qp + 32);
    f32x4 a3 = *(const f32x4*)(qp + 36);
#pragma unroll
    for (int j = 0; j < 4; ++j) {
      q0[j] = (__bf16)(a0[j] * 0.125f);
      q0[4 + j] = (__bf16)(a1[j] * 0.125f);
      q1[j] = (__bf16)(a2[j] * 0.125f);
      q1[4 + j] = (__bf16)(a3[j] * 0.125f);
    }
  }

  // ---- phase 1: S = (Q/8) Kt ; y[t][j] = rows (quad*4+2j, +2j+1), col l16 ----
  // y holds raw scores here; converted to y = negc0 - s after the max phase,
  // then updated in place by the Newton corrections.
  f32x2 y[TPW][2];
  {
    const __bf16* kb = kp + (size_t)bh * 131072;
#pragma unroll
    for (int t = 0; t < TPW; ++t) {
      const int ktile = w + WV * t;
      const size_t o = (size_t)ktile * 1024 + lane * 8;
      bf16x8 k0 = *(const bf16x8*)(kb + o);
      bf16x8 k1 = *(const bf16x8*)(kb + o + 512);
      f32x4 acc = {0.f, 0.f, 0.f, 0.f};
      acc = __builtin_amdgcn_mfma_f32_16x16x32_bf16(q0, k0, acc, 0, 0, 0);
      acc = __builtin_amdgcn_mfma_f32_16x16x32_bf16(q1, k1, acc, 0, 0, 0);
      y[t][0] = __builtin_shufflevector(acc, acc, 0, 1);
      y[t][1] = __builtin_shufflevector(acc, acc, 2, 3);
    }
  }

  // ---- phase 2: row max -> negc[j] = -c0 pairs (= max + 1); y := negc - s ----
  {
    f32x2 mx2[2] = {y[0][0], y[0][1]};
#pragma unroll
    for (int t = 1; t < TPW; ++t) {
#pragma unroll
      for (int j = 0; j < 2; ++j) {
        mx2[j].x = fmaxf(mx2[j].x, y[t][j].x);
        mx2[j].y = fmaxf(mx2[j].y, y[t][j].y);
      }
    }
#pragma unroll
    for (int j = 0; j < 2; ++j) {
      ROR_MAX(mx2[j].x, 8); ROR_MAX(mx2[j].x, 4); ROR_MAX(mx2[j].x, 2); ROR_MAX(mx2[j].x, 1);
      ROR_MAX(mx2[j].y, 8); ROR_MAX(mx2[j].y, 4); ROR_MAX(mx2[j].y, 2); ROR_MAX(mx2[j].y, 1);
    }
    if (l16 < 4) {
      float v = (l16 == 0) ? mx2[0].x : (l16 == 1) ? mx2[0].y
              : (l16 == 2) ? mx2[1].x : mx2[1].y;
      redmax[w][quad * 4 + l16] = v;
    }
    // zero the Newton atomic buffers under the same barrier
    if (tid < NEWTON * 16 * 2) ((float*)redn)[tid] = 0.f;
    __syncthreads();
    f32x2 negc[2];
#pragma unroll
    for (int r = 0; r < 4; ++r) {
      float m = redmax[l16 & 7][quad * 4 + r];
      ROR_MAX(m, 4); ROR_MAX(m, 2); ROR_MAX(m, 1);
      ((float*)negc)[r] = m + 1.0f;            // -c0 = max + 1
    }
    // convert scores -> y0 = negc0 - s  (in place)
#pragma unroll
    for (int t = 0; t < TPW; ++t) {
      y[t][0] = negc[0] - y[t][0];
      y[t][1] = negc[1] - y[t][1];
    }
  }

  // ---- phase 3: Newton x6 on c (packed-f32 inner loop; cross-wave via ds_add) ----
  for (int it = 0; it < NEWTON; ++it) {
    f32x2 ps2[2] = {{0.f, 0.f}, {0.f, 0.f}};
    f32x2 psd2[2] = {{0.f, 0.f}, {0.f, 0.f}};
#pragma unroll
    for (int t = 0; t < TPW; ++t) {
#pragma unroll
      for (int j = 0; j < 2; ++j) {
        f32x2 v = y[t][j];                     // y >= 1 along Newton path
        float z = __builtin_amdgcn_rcpf(v.x * v.y);
        f32x2 r1 = z * __builtin_shufflevector(v, v, 1, 0);  // (1/y.x, 1/y.y)
        f32x2 r2;
        asm("v_pk_mul_f32 %0, %1, %1" : "=v"(r2) : "v"(r1));
        asm("v_pk_add_f32 %0, %0, %1" : "+v"(ps2[j]) : "v"(r2));
        asm("v_pk_fma_f32 %0, %1, %2, %0" : "+v"(psd2[j]) : "v"(r2), "v"(r1));
      }
    }
#pragma unroll
    for (int j = 0; j < 2; ++j) {
      ROR_ADD(ps2[j].x, 8);  ROR_ADD(ps2[j].x, 4);  ROR_ADD(ps2[j].x, 2);  ROR_ADD(ps2[j].x, 1);
      ROR_ADD(ps2[j].y, 8);  ROR_ADD(ps2[j].y, 4);  ROR_ADD(ps2[j].y, 2);  ROR_ADD(ps2[j].y, 1);
      ROR_ADD(psd2[j].x, 8); ROR_ADD(psd2[j].x, 4); ROR_ADD(psd2[j].x, 2); ROR_ADD(psd2[j].x, 1);
      ROR_ADD(psd2[j].y, 8); ROR_ADD(psd2[j].y, 4); ROR_ADD(psd2[j].y, 2); ROR_ADD(psd2[j].y, 1);
    }
    if (l16 < 4) {
      float a = (l16 == 0) ? ps2[0].x : (l16 == 1) ? ps2[0].y
              : (l16 == 2) ? ps2[1].x : ps2[1].y;
      float d = (l16 == 0) ? psd2[0].x : (l16 == 1) ? psd2[0].y
              : (l16 == 2) ? psd2[1].x : psd2[1].y;
      atomicAdd(&redn[it][quad * 4 + l16][0], a);
      atomicAdd(&redn[it][quad * 4 + l16][1], d);
    }
    __syncthreads();
    f32x2 dd[2];
#pragma unroll
    for (int r = 0; r < 4; ++r) {
      const f32x2 v = *(const f32x2*)(&redn[it][quad * 4 + r][0]);
      ((float*)dd)[r] =
          (v.x - 1.0f) * __builtin_amdgcn_rcpf(2.0f * v.y + 1e-8f);
    }
#pragma unroll
    for (int t = 0; t < TPW; ++t) {
      y[t][0] += dd[0];
      y[t][1] += dd[1];
    }
  }

  // ---- phase 5: O = W * V; per-wave double-buffered bf16 weight slab ----
  // Weights for p-iter's two tiles (t=2p, 2p+1) are written one iteration
  // AHEAD into the alternate buffer, so the single lgkmcnt wait covers a
  // write whose latency was hidden by the previous iteration's MFMAs/loads.
  f32x4 oacc[4];
#pragma unroll
  for (int n = 0; n < 4; ++n) oacc[n] = (f32x4){0.f, 0.f, 0.f, 0.f};
  const __bf16* vpb = vp + (size_t)bh * 131072;

  // prologue: weights for tiles 0,1 -> buf 0
#pragma unroll
  for (int ts = 0; ts < 2; ++ts) {
    f32x2 a = y[ts][0];
    f32x2 bb = y[ts][1];
    float za = __builtin_amdgcn_rcpf(a.x * a.y);
    float zb = __builtin_amdgcn_rcpf(bb.x * bb.y);
    f32x2 ra = za * __builtin_shufflevector(a, a, 1, 0);
    f32x2 rb = zb * __builtin_shufflevector(bb, bb, 1, 0);
    f32x2 wa = ra * ra;
    f32x2 wb = rb * rb;
    pw[w].ws[0][quad * 4 + 0][ts * 16 + l16] = (__bf16)wa.x;
    pw[w].ws[0][quad * 4 + 1][ts * 16 + l16] = (__bf16)wa.y;
    pw[w].ws[0][quad * 4 + 2][ts * 16 + l16] = (__bf16)wb.x;
    pw[w].ws[0][quad * 4 + 3][ts * 16 + l16] = (__bf16)wb.y;
  }

#pragma unroll
  for (int p = 0; p < 8; ++p) {
    const size_t vo = ((size_t)(p * 8 + w) * 4) * 512 + lane * 8;
    // V loads (independent of slab) issue first
    bf16x8 v0 = *(const bf16x8*)(vpb + vo);
    bf16x8 v1 = *(const bf16x8*)(vpb + vo + 512);
    bf16x8 v2 = *(const bf16x8*)(vpb + vo + 1024);
    bf16x8 v3 = *(const bf16x8*)(vpb + vo + 1536);

    asm volatile("s_waitcnt lgkmcnt(0)" ::: "memory");  // slab writes visible
    // A-fragment: row l16, keys of tiles 2p (quads 0-1) / 2p+1 (quads 2-3):
    // col = (quad>>1)*16 + (quad&1)*8 + j == quad*8 + j.
    bf16x8 aw = *(const bf16x8*)(&pw[w].ws[p & 1][l16][quad * 8]);

    // write NEXT iteration's weights into the other buffer (no wait needed)
    if (p < 7) {
#pragma unroll
      for (int ts = 0; ts < 2; ++ts) {
        const int t = 2 * (p + 1) + ts;
        f32x2 a = y[t][0];
        f32x2 bb = y[t][1];
        float za = __builtin_amdgcn_rcpf(a.x * a.y);
        float zb = __builtin_amdgcn_rcpf(bb.x * bb.y);
        f32x2 ra = za * __builtin_shufflevector(a, a, 1, 0);
        f32x2 rb = zb * __builtin_shufflevector(bb, bb, 1, 0);
        f32x2 wa = ra * ra;
        f32x2 wb = rb * rb;
        pw[w].ws[(p + 1) & 1][quad * 4 + 0][ts * 16 + l16] = (__bf16)wa.x;
        pw[w].ws[(p + 1) & 1][quad * 4 + 1][ts * 16 + l16] = (__bf16)wa.y;
        pw[w].ws[(p + 1) & 1][quad * 4 + 2][ts * 16 + l16] = (__bf16)wb.x;
        pw[w].ws[(p + 1) & 1][quad * 4 + 3][ts * 16 + l16] = (__bf16)wb.y;
      }
    }

    oacc[0] = __builtin_amdgcn_mfma_f32_16x16x32_bf16(aw, v0, oacc[0], 0, 0, 0);
    oacc[1] = __builtin_amdgcn_mfma_f32_16x16x32_bf16(aw, v1, oacc[1], 0, 0, 0);
    oacc[2] = __builtin_amdgcn_mfma_f32_16x16x32_bf16(aw, v2, oacc[2], 0, 0, 0);
    oacc[3] = __builtin_amdgcn_mfma_f32_16x16x32_bf16(aw, v3, oacc[3], 0, 0, 0);
  }

  // ---- phase 6: reduce partials across waves, write global ----
#pragma unroll
  for (int n = 0; n < 4; ++n)
#pragma unroll
    for (int r = 0; r < 4; ++r)
      pw[w].ex[quad * 4 + r][n * 16 + l16] = oacc[n][r];
  __syncthreads();
  {
    const int row = 2 * w + (lane >> 5);
    const int d = lane & 31;
    float v0 = 0.f, v1 = 0.f;
#pragma unroll
    for (int i = 0; i < WV; ++i) {
      v0 += pw[i].ex[row][d];
      v1 += pw[i].ex[row][d + 32];
    }
    const int off = ((b * NL + qbase + row) * NH + h) * ND + d;
    outg[off] = v0;
    outg[off + 32] = v1;
  }
}

extern "C" void kernel_launch(void* const* d_in, const int* in_sizes, int n_in,
                              void* d_out, int out_size, void* d_ws, size_t ws_size,
                              hipStream_t stream) {
  const float* q = (const float*)d_in[0];
  const float* k = (const float*)d_in[1];
  const float* v = (const float*)d_in[2];

  const size_t plane = (size_t)NB * NH * ND * NL;  // 3.15M elems, 6.29MB/plane
  __bf16* kp = (__bf16*)d_ws;
  __bf16* vp = kp + plane;

  prep<<<NB * 128 * 3 * 2, 256, 0, stream>>>(k, v, kp, vp);

  attn_poly<<<NB * NH * (NL / 16), 512, 0, stream>>>(
      q, kp, vp, (float*)d_out);
}